// Round 1
// baseline (4485.409 us; speedup 1.0000x reference)
//
#include <hip/hip_runtime.h>
#include <math.h>

// ---------------------------------------------------------------------------
// SO2 equivariant graph attention, fp32 baseline.
// Shapes: N=10000 nodes, E=100000 edges, L2=16 coeffs, C=64, H=32, R=64.
// Row order (slot s -> wigner row IDX[s]); equals vals row order:
//   M0={0,2,6,12}, M1P={3,7,13}, M1N={1,5,11}, M2P={8,14}, M2N={4,10}
// ---------------------------------------------------------------------------

__constant__ int c_ROWS14[14] = {0,2,6,12, 3,7,13, 1,5,11, 8,14, 4,10};

__device__ __forceinline__ unsigned enc_f(float f){
  unsigned u = __float_as_uint(f);
  return (u & 0x80000000u) ? ~u : (u | 0x80000000u);
}
__device__ __forceinline__ float dec_f(unsigned u){
  return (u & 0x80000000u) ? __uint_as_float(u & 0x7fffffffu)
                           : __uint_as_float(~u);
}

// ------------------------------ init ---------------------------------------
__global__ void k_init(float* __restrict__ agg, unsigned* __restrict__ mxe,
                       float* __restrict__ den, int N){
  const int idx = blockIdx.x*256 + threadIdx.x;
  if(idx < N*512) agg[idx] = 0.f;
  if(idx < N*8){ mxe[idx] = 0u; den[idx] = 0.f; }
}

// ------------------------------ gate ---------------------------------------
// gate = sigmoid( silu(rbf @ Wr1) @ Wr2 ), per edge.  4 edges/block.
__global__ __launch_bounds__(256)
void k_gate(const float* __restrict__ rbf, const float* __restrict__ Wr1,
            const float* __restrict__ Wr2, float* __restrict__ gate){
  __shared__ float s_r[4][64];
  __shared__ float s_t[4][64];
  const int le = threadIdx.x >> 6, ln = threadIdx.x & 63;
  const int e = blockIdx.x*4 + le;
  s_r[le][ln] = rbf[(size_t)e*64 + ln];
  __syncthreads();
  float acc = 0.f;
  #pragma unroll 8
  for(int k=0;k<64;k++) acc = fmaf(s_r[le][k], Wr1[k*64+ln], acc);
  const float sg = 1.f/(1.f + __expf(-acc));
  s_t[le][ln] = acc*sg;                      // silu
  __syncthreads();
  if(ln < 32){
    float a2 = 0.f;
    #pragma unroll 8
    for(int k=0;k<64;k++) a2 = fmaf(s_t[le][k], Wr2[k*32+ln], a2);
    gate[(size_t)e*32 + ln] = 1.f/(1.f + __expf(-a2));
  }
}

// ------------------------------ logits -------------------------------------
// Needs only row 0 of y0: a0 = xr rows {0,2,6,12} (512 vals) dotted with
// W0[:, 0..31], times gate, leaky_relu, dot alpha per head.  8 edges/block.
__global__ __launch_bounds__(256)
void k_logit(const float* __restrict__ x, const float* __restrict__ wig,
             const float* __restrict__ gate, const float* __restrict__ W0,
             const float* __restrict__ alpha, const int* __restrict__ src,
             const int* __restrict__ dst, float* __restrict__ logits){
  __shared__ float sA0[8][512];
  __shared__ float sW[8][64];
  __shared__ int sS[8], sD[8];
  const int t = threadIdx.x;
  const int e0 = blockIdx.x*8;
  if(t < 8){ sS[t] = src[e0+t]; sD[t] = dst[e0+t]; }
  #pragma unroll
  for(int p=0;p<2;p++){
    const int tau = p*256 + t;               // 512 wigner vals (4 rows x 16 x 8e)
    const int el = tau>>6, q = tau&63;
    sW[el][q] = wig[(size_t)(e0+el)*256 + c_ROWS14[q>>4]*16 + (q&15)];
  }
  __syncthreads();
  // rotate rows M0 for all 8 edges: tasks (el, c) = 1024
  #pragma unroll
  for(int p=0;p<4;p++){
    const int tau = p*256 + t;
    const int el = tau>>7, c = tau&127;
    const int node = (c < 64) ? sS[el] : sD[el];
    const float* xp = x + (size_t)node*1024 + (c & 63);
    float xe[16];
    #pragma unroll
    for(int j=0;j<16;j++) xe[j] = xp[j*64];
    #pragma unroll
    for(int r=0;r<4;r++){
      float a = 0.f;
      #pragma unroll
      for(int j=0;j<16;j++) a = fmaf(sW[el][r*16+j], xe[j], a);
      sA0[el][r*128 + c] = a;
    }
  }
  __syncthreads();
  const int el = t>>5, h = t&31;
  float y = 0.f;
  #pragma unroll 8
  for(int k=0;k<512;k++) y = fmaf(sA0[el][k], W0[(size_t)k*128 + h], y);
  y *= gate[(size_t)(e0+el)*32 + h];
  const float z = (y > 0.f) ? y : 0.2f*y;    // leaky_relu 0.2
  float ct = z * alpha[h];                   // alpha[(h>>2)*4 + (h&3)] == alpha[h]
  ct += __shfl_xor(ct, 1);
  ct += __shfl_xor(ct, 2);
  if((h & 3) == 0) logits[(size_t)(e0+el)*8 + (h>>2)] = ct;
}

// --------------------------- segment softmax -------------------------------
__global__ void k_max(const float* __restrict__ logits, const int* __restrict__ dst,
                      unsigned* __restrict__ mxe, int E8){
  const int idx = blockIdx.x*256 + threadIdx.x;
  if(idx >= E8) return;
  const int e = idx>>3, hd = idx&7;
  atomicMax(&mxe[(size_t)dst[e]*8 + hd], enc_f(logits[idx]));
}
__global__ void k_den(const float* __restrict__ logits, const int* __restrict__ dst,
                      const unsigned* __restrict__ mxe, float* __restrict__ den, int E8){
  const int idx = blockIdx.x*256 + threadIdx.x;
  if(idx >= E8) return;
  const int e = idx>>3, hd = idx&7;
  const float m = dec_f(mxe[(size_t)dst[e]*8 + hd]);
  atomicAdd(&den[(size_t)dst[e]*8 + hd], __expf(logits[idx] - m));
}

// ------------------------------ main ---------------------------------------
// 32 edges/block, 512 threads.  LDS:
//   sWig [32][225] (14 rows x 16, stride 225 vs 224 to avoid bank conflicts)
//   sA   [384][32] (k_local x edge), built per 64-col half (src / dst)
//   sB   [32][NOUT] staged per (r, 32-k subchunk), signs folded in
//   sVal [32][452]  (14x32 raw y values, stride padded)
template<int G>
__device__ __forceinline__ void so2_group(
    float* __restrict__ sWig, float* __restrict__ sA, float* __restrict__ sB,
    float* __restrict__ sVal, const int* __restrict__ sSrc, const int* __restrict__ sDst,
    const float* __restrict__ x,
    const float* __restrict__ W0, const float* __restrict__ W1r, const float* __restrict__ W1i,
    const float* __restrict__ W2r, const float* __restrict__ W2i)
{
  constexpr int NR    = (G==1) ? 6 : 4;
  constexpr int NOUT  = (G==1) ? 192 : 128;
  constexpr int NO    = (G==1) ? 3 : 2;
  constexpr int SBASE = (G==0) ? 0 : ((G==1) ? 4 : 10);
  constexpr int VBASE = (G==0) ? 0 : ((G==1) ? 128 : 320);
  const int t  = threadIdx.x;
  const int et = t>>6, ot = t&63;
  const int e4 = et*4;
  const int o0 = (G==1) ? ((ot<32) ? ot*3 : 96 + (ot-32)*3) : ot*2;
  float acc[4][NO];
  #pragma unroll
  for(int i=0;i<4;i++)
    #pragma unroll
    for(int j=0;j<NO;j++) acc[i][j] = 0.f;

  const int bel = t & 31;        // build: edge (fastest -> conflict-free ds_write)
  const int bc4 = t >> 5;        // build: col-quad 0..15

  for(int half=0; half<2; half++){
    __syncthreads();             // sA free (prev sub-gemm / prev group done)
    // ---- build rotated A for this 64-col half; x loads reused across rows ----
    {
      const int node = half ? sDst[bel] : sSrc[bel];
      const float* xp = x + (size_t)node*1024 + bc4*4;
      const float* wr = &sWig[bel*225 + SBASE*16];
      float4 a[NR];
      #pragma unroll
      for(int r=0;r<NR;r++){ a[r].x=0.f; a[r].y=0.f; a[r].z=0.f; a[r].w=0.f; }
      #pragma unroll
      for(int j=0;j<16;j++){
        const float4 xv = *(const float4*)(xp + j*64);
        #pragma unroll
        for(int r=0;r<NR;r++){
          const float w = wr[r*16 + j];
          a[r].x = fmaf(w, xv.x, a[r].x); a[r].y = fmaf(w, xv.y, a[r].y);
          a[r].z = fmaf(w, xv.z, a[r].z); a[r].w = fmaf(w, xv.w, a[r].w);
        }
      }
      #pragma unroll
      for(int r=0;r<NR;r++){
        const int kl = r*64 + bc4*4;
        sA[(kl+0)*32 + bel] = a[r].x; sA[(kl+1)*32 + bel] = a[r].y;
        sA[(kl+2)*32 + bel] = a[r].z; sA[(kl+3)*32 + bel] = a[r].w;
      }
    }
    for(int r=0;r<NR;r++){
      #pragma unroll
      for(int sub=0; sub<2; sub++){
        __syncthreads();         // prev gemm done -> sB reusable; (r=0,sub=0) covers sA build
        // ---- stage B subchunk: rows k = r*128 + half*64 + sub*32 + cc ----
        {
          constexpr int NT = 32*NOUT/4;          // 1024 or 1536 float4 tasks
          #pragma unroll
          for(int p=0; p<NT/512; p++){
            const int tau = p*512 + t;
            const int o4  = tau % (NOUT/4);
            const int cc  = tau / (NOUT/4);
            const int o   = o4*4;
            const int cabs = half*64 + sub*32 + cc;
            float4 v;
            if(G==0){
              v = *(const float4*)&W0[(size_t)(r*128 + cabs)*128 + o];
            } else if(G==1){
              const int k1 = ((r<3) ? r : (r-3))*128 + cabs;
              if(o < 96){
                if(r < 3) v = *(const float4*)&W1r[(size_t)k1*96 + o];
                else { v = *(const float4*)&W1i[(size_t)k1*96 + o];
                       v.x=-v.x; v.y=-v.y; v.z=-v.z; v.w=-v.w; }
              } else {
                const int oo = o - 96;
                if(r < 3) v = *(const float4*)&W1i[(size_t)k1*96 + oo];
                else      v = *(const float4*)&W1r[(size_t)k1*96 + oo];
              }
            } else {
              const int k2 = ((r<2) ? r : (r-2))*128 + cabs;
              if(o < 64){
                if(r < 2) v = *(const float4*)&W2r[(size_t)k2*64 + o];
                else { v = *(const float4*)&W2i[(size_t)k2*64 + o];
                       v.x=-v.x; v.y=-v.y; v.z=-v.z; v.w=-v.w; }
              } else {
                const int oo = o - 64;
                if(r < 2) v = *(const float4*)&W2i[(size_t)k2*64 + oo];
                else      v = *(const float4*)&W2r[(size_t)k2*64 + oo];
              }
            }
            *(float4*)&sB[cc*NOUT + o] = v;
          }
        }
        __syncthreads();
        // ---- register-tile GEMM over 32 k's ----
        #pragma unroll 8
        for(int cc=0; cc<32; cc++){
          const float4 a = *(const float4*)&sA[(r*64 + sub*32 + cc)*32 + e4];
          const float* bp = &sB[cc*NOUT + o0];
          #pragma unroll
          for(int j=0;j<NO;j++){
            const float b = bp[j];
            acc[0][j] = fmaf(a.x, b, acc[0][j]);
            acc[1][j] = fmaf(a.y, b, acc[1][j]);
            acc[2][j] = fmaf(a.z, b, acc[2][j]);
            acc[3][j] = fmaf(a.w, b, acc[3][j]);
          }
        }
      }
    }
  }
  // ---- dump raw y values (gate & attn applied later, they're per-h only) ----
  #pragma unroll
  for(int i=0;i<4;i++)
    #pragma unroll
    for(int j=0;j<NO;j++)
      sVal[(size_t)(e4+i)*452 + VBASE + o0 + j] = acc[i][j];
}

#define K_MAIN_LDS ((7200 + 12288 + 6144 + 14464 + 64) * 4)

__global__ __launch_bounds__(512, 1)
void k_main(const float* __restrict__ x, const float* __restrict__ wig,
            const float* __restrict__ W0, const float* __restrict__ W1r,
            const float* __restrict__ W1i, const float* __restrict__ W2r,
            const float* __restrict__ W2i, const float* __restrict__ gate,
            const float* __restrict__ logits, const unsigned* __restrict__ mxe,
            const float* __restrict__ den, const int* __restrict__ src,
            const int* __restrict__ dst, float* __restrict__ agg)
{
  extern __shared__ float lds[];
  float* sWig = lds;                    // 32*225 = 7200
  float* sA   = sWig + 7200;            // 384*32 = 12288
  float* sB   = sA   + 12288;           // 32*192 = 6144
  float* sVal = sB   + 6144;            // 32*452 = 14464
  int*   sSrc = (int*)(sVal + 14464);   // 32
  int*   sDst = sSrc + 32;              // 32
  const int t  = threadIdx.x;
  const int e0 = blockIdx.x * 32;

  if(t < 32){ sSrc[t] = src[e0+t]; sDst[t] = dst[e0+t]; }
  #pragma unroll
  for(int p=0;p<14;p++){                // 7168 wigner values (14 rows x 16 x 32e)
    const int tau = p*512 + t;
    const int el = tau/224, q = tau%224;
    sWig[el*225 + q] = wig[(size_t)(e0+el)*256 + c_ROWS14[q>>4]*16 + (q&15)];
  }
  __syncthreads();

  so2_group<0>(sWig,sA,sB,sVal,sSrc,sDst,x,W0,W1r,W1i,W2r,W2i);
  so2_group<1>(sWig,sA,sB,sVal,sSrc,sDst,x,W0,W1r,W1i,W2r,W2i);
  so2_group<2>(sWig,sA,sB,sVal,sSrc,sDst,x,W0,W1r,W1i,W2r,W2i);
  __syncthreads();

  // ---- inverse rotation (wigner^T) + gate*attn weighting + scatter ----
  const int el = t>>4, i = t&15;        // 32 edges x 16 output rows
  const int dn = sDst[el];
  float at[8];
  #pragma unroll
  for(int hd=0;hd<8;hd++){
    const float lg = logits[(size_t)(e0+el)*8 + hd];
    const float m  = dec_f(mxe[(size_t)dn*8 + hd]);
    at[hd] = __expf(lg - m) / den[(size_t)dn*8 + hd];
  }
  float wc[14];
  #pragma unroll
  for(int s=0;s<14;s++) wc[s] = sWig[el*225 + s*16 + i];
  float msg[32];
  #pragma unroll
  for(int h=0;h<32;h++) msg[h] = 0.f;
  #pragma unroll
  for(int s=0;s<14;s++){
    const float* vp = &sVal[(size_t)el*452 + s*32];
    const float w = wc[s];
    #pragma unroll
    for(int h=0;h<32;h++) msg[h] = fmaf(w, vp[h], msg[h]);
  }
  const float* gp = gate + (size_t)(e0+el)*32;
  float* ag = agg + (size_t)dn*512 + i*32;
  #pragma unroll
  for(int h=0;h<32;h++)
    atomicAdd(&ag[h], msg[h] * gp[h] * at[h>>2]);
}

// ------------------------------ output -------------------------------------
__global__ __launch_bounds__(256)
void k_out(const float* __restrict__ agg, const float* __restrict__ Wout,
           float* __restrict__ out, int total){
  const int idx = blockIdx.x*256 + threadIdx.x;
  if(idx >= total) return;
  const int c = idx & 63, row = idx >> 6;       // row = n*16+i
  const float* ap = agg + (size_t)row*32;
  float a = 0.f;
  #pragma unroll
  for(int h=0;h<32;h++) a = fmaf(ap[h], Wout[h*64 + c], a);
  out[idx] = a;
}

// ---------------------------------------------------------------------------
extern "C" void kernel_launch(void* const* d_in, const int* in_sizes, int n_in,
                              void* d_out, int out_size, void* d_ws, size_t ws_size,
                              hipStream_t stream){
  const float* x     = (const float*)d_in[0];
  const float* wig   = (const float*)d_in[1];
  const float* rbf   = (const float*)d_in[2];
  const float* W0    = (const float*)d_in[3];
  const float* W1r   = (const float*)d_in[4];
  const float* W1i   = (const float*)d_in[5];
  const float* W2r   = (const float*)d_in[6];
  const float* W2i   = (const float*)d_in[7];
  const float* Wr1   = (const float*)d_in[8];
  const float* Wr2   = (const float*)d_in[9];
  const float* alpha = (const float*)d_in[10];
  const float* Wout  = (const float*)d_in[11];
  const int*   src   = (const int*)d_in[12];
  const int*   dst   = (const int*)d_in[13];
  float* out = (float*)d_out;

  const int E = in_sizes[12];
  const int N = in_sizes[0] / 1024;       // x is [N,16,64]

  // workspace layout (floats): gate E*32 | logits E*8 | mxe N*8 | den N*8 | agg N*512
  float*    ws     = (float*)d_ws;
  float*    gate   = ws;
  float*    logits = ws + (size_t)E*32;
  unsigned* mxe    = (unsigned*)(ws + (size_t)E*40);
  float*    den    = ws + (size_t)E*40 + (size_t)N*8;
  float*    agg    = ws + (size_t)E*40 + (size_t)N*16;

  hipFuncSetAttribute((const void*)k_main,
                      hipFuncAttributeMaxDynamicSharedMemorySize, K_MAIN_LDS);

  k_init <<<(N*512 + 255)/256, 256, 0, stream>>>(agg, mxe, den, N);
  k_gate <<<E/4, 256, 0, stream>>>(rbf, Wr1, Wr2, gate);
  k_logit<<<E/8, 256, 0, stream>>>(x, wig, gate, W0, alpha, src, dst, logits);
  k_max  <<<(E*8 + 255)/256, 256, 0, stream>>>(logits, dst, mxe, E*8);
  k_den  <<<(E*8 + 255)/256, 256, 0, stream>>>(logits, dst, mxe, den, E*8);
  k_main <<<E/32, 512, K_MAIN_LDS, stream>>>(x, wig, W0, W1r, W1i, W2r, W2i,
                                             gate, logits, mxe, den, src, dst, agg);
  k_out  <<<(N*1024 + 255)/256, 256, 0, stream>>>(agg, Wout, out, N*1024);
}